// Round 9
// baseline (286.412 us; speedup 1.0000x reference)
//
#include <hip/hip_runtime.h>
#include <math.h>

// ---------------------------------------------------------------------------
// Pipeline v5 — two-level dst sort + scalar-CSR aggregation, widened loads.
// Empirical model (r5-r8): gather kernels pin at ~0.5-0.6 VMEM addresses per
// cyc per CU; minimize issued addresses, not bytes.
//   k_bucket : radix pass 1 (dst>>10). SINGLE LDS atomic/edge: rank-first
//              (ranks reg-cached), final rk[] doubles as histogram. Shuffle
//              scan, coalesced per-wave run write-out.
//   k_sort   : radix pass 2 (dst&1023) per bucket; rank atomic == degree
//              histogram; in-place coalesced write-back of sorted src; CSR
//              start[]; fused dinv/u=bf16(x*dinv) epilogue.
//   k_agg1   : thread=node scalar CSR walk, uint4-middle (head/tail scalar,
//              dwordx4 middle: ~6 file addrs/node vs 16), gather u (bf16),
//              MLP 1->16->2, q packed 2xbf16.
//   k_agg2   : same walk on q; +self, *dinv, +b2, log_softmax.
// ---------------------------------------------------------------------------

typedef unsigned int uint4v __attribute__((ext_vector_type(4)));

#define NPB 1024            // nodes per bucket
#define NPB_SHIFT 10
#define NPB_MASK (NPB - 1)
#define MAXB 512            // max buckets
#define P1T 512             // k_bucket threads
#define CHUNK 16384         // edges per k_bucket block
#define EPT 32              // CHUNK / P1T edges per thread
#define SORT_CAP 17408      // per-bucket file capacity
#define SPT 17              // SORT_CAP / 1024 entries per k_sort thread

#define NTL4(p) __builtin_nontemporal_load((const uint4v*)(p))

__device__ __forceinline__ unsigned short f2bf(float f) {
    unsigned int x = __float_as_uint(f);
    x += 0x7fffu + ((x >> 16) & 1u);            // round-to-nearest-even
    return (unsigned short)(x >> 16);
}
__device__ __forceinline__ float bf2f(unsigned short h) {
    return __uint_as_float((unsigned int)h << 16);
}

// ---------------------------------------------------------------------------
// Phase 1: bucket by dst>>10. One LDS atomic per edge (rank-first).
// ---------------------------------------------------------------------------
__global__ __launch_bounds__(P1T) void k_bucket(
    const int* __restrict__ src, const int* __restrict__ dst,
    unsigned int* __restrict__ file, int* __restrict__ ctr,
    int E, int nbucket, int cap)
{
    __shared__ unsigned int sorted[CHUNK];   // 64 KB
    __shared__ int rk[MAXB];                 // rank counters -> histogram
    __shared__ int pre[MAXB + 1];
    __shared__ int gb[MAXB];
    __shared__ int wsum[P1T / 64];

    const int t  = threadIdx.x;
    const int e0 = blockIdx.x * CHUNK;
    const int nE = min(CHUNK, E - e0);

    for (int b = t; b < MAXB; b += P1T) rk[b] = 0;
    __syncthreads();

    const bool full = (nE == CHUNK);
    int4 dc[8];          // cached dst
    int  rnk[EPT];       // cached ranks

    // ---- pass 1: rank assignment (doubles as histogram) ----
    if (full) {
        const int4* d4 = (const int4*)(dst + e0);
#pragma unroll
        for (int k = 0; k < 8; ++k) dc[k] = d4[t + k * P1T];
#pragma unroll
        for (int k = 0; k < 8; ++k) {
            rnk[4 * k]     = atomicAdd(&rk[((unsigned)dc[k].x) >> NPB_SHIFT], 1);
            rnk[4 * k + 1] = atomicAdd(&rk[((unsigned)dc[k].y) >> NPB_SHIFT], 1);
            rnk[4 * k + 2] = atomicAdd(&rk[((unsigned)dc[k].z) >> NPB_SHIFT], 1);
            rnk[4 * k + 3] = atomicAdd(&rk[((unsigned)dc[k].w) >> NPB_SHIFT], 1);
        }
    } else {
        int k = 0;
        for (int i = t; i < nE; i += P1T, ++k)
            rnk[k] = atomicAdd(&rk[((unsigned)dst[e0 + i]) >> NPB_SHIFT], 1);
    }
    __syncthreads();

    // ---- hierarchical inclusive scan of rk -> pre (3 barriers) ----
    {
        const int lane = t & 63, wv = t >> 6;
        int v = (t < nbucket) ? rk[t] : 0;
#pragma unroll
        for (int d = 1; d < 64; d <<= 1) {
            int nv = __shfl_up(v, d, 64);
            if (lane >= d) v += nv;
        }
        if (lane == 63) wsum[wv] = v;
        __syncthreads();
        if (t < P1T / 64) {
            int s = wsum[t];
#pragma unroll
            for (int d = 1; d < P1T / 64; d <<= 1) {
                int ns = __shfl_up(s, d, P1T / 64);
                if (t >= d) s += ns;
            }
            wsum[t] = s;
        }
        __syncthreads();
        pre[t + 1] = (wv ? wsum[wv - 1] : 0) + v;
        if (t == 0) pre[0] = 0;
    }
    __syncthreads();

    // ---- reserve global space per (block,bucket) ----
    for (int b = t; b < nbucket; b += P1T) {
        int c = pre[b + 1] - pre[b];
        gb[b] = c ? atomicAdd(&ctr[b], c) : 0;
    }
    __syncthreads();

    // ---- pass 2: scatter into LDS using saved ranks (no atomics) ----
    if (full) {
        const int4* s4 = (const int4*)(src + e0);
#pragma unroll
        for (int k = 0; k < 8; ++k) {
            int4 s = s4[t + k * P1T];
            int4 d = dc[k];
            sorted[pre[((unsigned)d.x) >> NPB_SHIFT] + rnk[4 * k]] =
                (((unsigned)s.x) << NPB_SHIFT) | ((unsigned)d.x & NPB_MASK);
            sorted[pre[((unsigned)d.y) >> NPB_SHIFT] + rnk[4 * k + 1]] =
                (((unsigned)s.y) << NPB_SHIFT) | ((unsigned)d.y & NPB_MASK);
            sorted[pre[((unsigned)d.z) >> NPB_SHIFT] + rnk[4 * k + 2]] =
                (((unsigned)s.z) << NPB_SHIFT) | ((unsigned)d.z & NPB_MASK);
            sorted[pre[((unsigned)d.w) >> NPB_SHIFT] + rnk[4 * k + 3]] =
                (((unsigned)s.w) << NPB_SHIFT) | ((unsigned)d.w & NPB_MASK);
        }
    } else {
        int k = 0;
        for (int i = t; i < nE; i += P1T, ++k) {
            int d = dst[e0 + i];
            int b = ((unsigned)d) >> NPB_SHIFT;
            sorted[pre[b] + rnk[k]] =
                (((unsigned)src[e0 + i]) << NPB_SHIFT) | ((unsigned)d & NPB_MASK);
        }
    }
    __syncthreads();

    // ---- pass 3: per-wave run write-out, clamped to cap ----
    {
        const int wid  = t >> 6;
        const int lane = t & 63;
        const int nw   = P1T >> 6;
        for (int b = wid; b < nbucket; b += nw) {
            int s0 = pre[b], s1 = pre[b + 1];
            int base = gb[b];
            unsigned int* dp = file + (size_t)b * cap;
            for (int j = s0 + lane; j < s1; j += 64) {
                int idx = base + (j - s0);
                if (idx < cap)
                    __builtin_nontemporal_store(sorted[j], &dp[idx]);
            }
        }
    }
}

// ---------------------------------------------------------------------------
// Phase 2: per-bucket sort by dstlo; rank atomic == degree histogram.
// ---------------------------------------------------------------------------
__global__ __launch_bounds__(NPB) void k_sort(
    unsigned int* __restrict__ file, const int* __restrict__ ctr,
    int* __restrict__ start, const float* __restrict__ x,
    float* __restrict__ dinv, unsigned short* __restrict__ u,
    int N, int cap)
{
    __shared__ unsigned int sorted[SORT_CAP];  // 69.6 KB
    __shared__ int cnt[NPB];
    __shared__ int pre[NPB + 1];
    __shared__ int wsum[NPB / 64];

    const int t = threadIdx.x;
    const int b = blockIdx.x;
    const int nb = min(ctr[b], cap);
    unsigned int* f = file + (size_t)b * cap;

    cnt[t] = 0;
    __syncthreads();

    unsigned int ev[SPT];
    int rk_[SPT];
#pragma unroll
    for (int k = 0; k < SPT; ++k) {
        int i = t + (k << NPB_SHIFT);
        if (i < nb) ev[k] = __builtin_nontemporal_load(f + i);
    }
#pragma unroll
    for (int k = 0; k < SPT; ++k) {
        int i = t + (k << NPB_SHIFT);
        if (i < nb) rk_[k] = atomicAdd(&cnt[ev[k] & NPB_MASK], 1);
    }
    __syncthreads();

    // hierarchical inclusive scan of cnt -> pre (3 barriers)
    {
        const int lane = t & 63, wv = t >> 6;
        int v = cnt[t];
#pragma unroll
        for (int d = 1; d < 64; d <<= 1) {
            int nv = __shfl_up(v, d, 64);
            if (lane >= d) v += nv;
        }
        if (lane == 63) wsum[wv] = v;
        __syncthreads();
        if (t < NPB / 64) {
            int s = wsum[t];
#pragma unroll
            for (int d = 1; d < NPB / 64; d <<= 1) {
                int ns = __shfl_up(s, d, NPB / 64);
                if (t >= d) s += ns;
            }
            wsum[t] = s;
        }
        __syncthreads();
        pre[t + 1] = (wv ? wsum[wv - 1] : 0) + v;
        if (t == 0) pre[0] = 0;
    }
    __syncthreads();

    // scatter src into dst-sorted LDS order
#pragma unroll
    for (int k = 0; k < SPT; ++k) {
        int i = t + (k << NPB_SHIFT);
        if (i < nb)
            sorted[pre[ev[k] & NPB_MASK] + rk_[k]] = ev[k] >> NPB_SHIFT;
    }
    __syncthreads();

    // coalesced in-place write-back
    for (int i = t; i < nb; i += NPB)
        __builtin_nontemporal_store(sorted[i], &f[i]);

    // CSR offsets
    start[b * (NPB + 1) + t] = pre[t];
    if (t == 0) start[b * (NPB + 1) + NPB] = pre[NPB];

    // node epilogue
    const int g = b * NPB + t;
    if (g < N) {
        float dv = rsqrtf((float)(cnt[t] + 1));   // +1 self-loop
        dinv[g] = dv;
        u[g] = f2bf(x[g] * dv);
    }
}

// ---------------------------------------------------------------------------
// Phase 3: scalar-CSR agg1 with uint4-middle walk -> MLP -> q (2xbf16).
// ---------------------------------------------------------------------------
__global__ __launch_bounds__(256) void k_agg1(
    const unsigned int* __restrict__ file, const int* __restrict__ start,
    const unsigned short* __restrict__ u, const float* __restrict__ dinv,
    const float* __restrict__ W1, const float* __restrict__ b1,
    const float* __restrict__ W2, unsigned int* __restrict__ q,
    int N, int cap)
{
    int g = blockIdx.x * 256 + threadIdx.x;
    if (g >= N) return;
    int b = g >> NPB_SHIFT, loc = g & NPB_MASK;
    const int* st = start + b * (NPB + 1);
    int e0 = st[loc], e1 = st[loc + 1];
    const unsigned int* f = file + (size_t)b * cap;

    float acc = 0.f;
    int j = e0;
    int ja = (e0 + 3) & ~3;   // first 16B-aligned index
    int jb = e1 & ~3;         // last aligned block end
    if (ja > jb) ja = e1;     // tiny segment: all scalar
    for (; j < ja; ++j) acc += bf2f(u[__builtin_nontemporal_load(f + j)]);
    for (; j < jb; j += 4) {
        uint4v w = NTL4(f + j);
        float v0 = bf2f(u[w.x]), v1 = bf2f(u[w.y]);
        float v2 = bf2f(u[w.z]), v3 = bf2f(u[w.w]);
        acc += (v0 + v1) + (v2 + v3);
    }
    for (; j < e1; ++j) acc += bf2f(u[__builtin_nontemporal_load(f + j)]);

    float dv = dinv[g];
    float s1v = (acc + bf2f(u[g])) * dv;
    float c0 = 0.f, c1 = 0.f;
#pragma unroll
    for (int k = 0; k < 16; ++k) {
        float h = fmaxf(fmaf(s1v, W1[k], b1[k]), 0.f);
        c0 = fmaf(h, W2[2 * k], c0);
        c1 = fmaf(h, W2[2 * k + 1], c1);
    }
    q[g] = (unsigned int)f2bf(c0 * dv) | ((unsigned int)f2bf(c1 * dv) << 16);
}

// ---------------------------------------------------------------------------
// Phase 4: scalar-CSR agg2 with uint4-middle walk -> log_softmax.
// ---------------------------------------------------------------------------
__global__ __launch_bounds__(256) void k_agg2(
    const unsigned int* __restrict__ file, const int* __restrict__ start,
    const unsigned int* __restrict__ q, const float* __restrict__ dinv,
    const float* __restrict__ b2, float2* __restrict__ out,
    int N, int cap)
{
    int g = blockIdx.x * 256 + threadIdx.x;
    if (g >= N) return;
    int b = g >> NPB_SHIFT, loc = g & NPB_MASK;
    const int* st = start + b * (NPB + 1);
    int e0 = st[loc], e1 = st[loc + 1];
    const unsigned int* f = file + (size_t)b * cap;

    float a0 = 0.f, a1 = 0.f;
    int j = e0;
    int ja = (e0 + 3) & ~3;
    int jb = e1 & ~3;
    if (ja > jb) ja = e1;
    for (; j < ja; ++j) {
        unsigned int gq = q[__builtin_nontemporal_load(f + j)];
        a0 += bf2f((unsigned short)gq);
        a1 += bf2f((unsigned short)(gq >> 16));
    }
    for (; j < jb; j += 4) {
        uint4v w = NTL4(f + j);
        unsigned int g0 = q[w.x], g1 = q[w.y], g2 = q[w.z], g3 = q[w.w];
        a0 += (bf2f((unsigned short)g0) + bf2f((unsigned short)g1)) +
              (bf2f((unsigned short)g2) + bf2f((unsigned short)g3));
        a1 += (bf2f((unsigned short)(g0 >> 16)) + bf2f((unsigned short)(g1 >> 16))) +
              (bf2f((unsigned short)(g2 >> 16)) + bf2f((unsigned short)(g3 >> 16)));
    }
    for (; j < e1; ++j) {
        unsigned int gq = q[__builtin_nontemporal_load(f + j)];
        a0 += bf2f((unsigned short)gq);
        a1 += bf2f((unsigned short)(gq >> 16));
    }

    float dv = dinv[g];
    unsigned int qi = q[g];
    float o0 = (a0 + bf2f((unsigned short)qi)) * dv + b2[0];
    float o1 = (a1 + bf2f((unsigned short)(qi >> 16))) * dv + b2[1];
    float m = fmaxf(o0, o1);
    float l = m + logf(expf(o0 - m) + expf(o1 - m));
    out[g] = make_float2(o0 - l, o1 - l);
}

// ===========================================================================
// Fallback path (direct-atomic, fp32) if workspace/shape doesn't fit.
// ===========================================================================
#define NT 256
__global__ __launch_bounds__(NT) void fb_deg(const int* __restrict__ dst,
                                             int* __restrict__ deg, int E) {
    int e = blockIdx.x * blockDim.x + threadIdx.x;
    if (e < E) atomicAdd(&deg[dst[e]], 1);
}
__global__ __launch_bounds__(NT) void fb_node1(const float* __restrict__ x,
                                               const int* __restrict__ deg,
                                               float* __restrict__ dinv,
                                               float* __restrict__ u, int N) {
    int i = blockIdx.x * blockDim.x + threadIdx.x;
    if (i < N) {
        float dv = rsqrtf((float)(deg[i] + 1));
        dinv[i] = dv;
        u[i] = x[i] * dv;
    }
}
__global__ __launch_bounds__(NT) void fb_edge1(const int* __restrict__ src,
                                               const int* __restrict__ dst,
                                               const float* __restrict__ u,
                                               float* __restrict__ agg1, int E) {
    int e = blockIdx.x * blockDim.x + threadIdx.x;
    if (e < E) atomicAdd(&agg1[dst[e]], u[src[e]]);
}
__global__ __launch_bounds__(NT) void fb_node2(const float* __restrict__ agg1,
                                               const float* __restrict__ u,
                                               const float* __restrict__ dinv,
                                               const float* __restrict__ W1,
                                               const float* __restrict__ b1,
                                               const float* __restrict__ W2,
                                               float2* __restrict__ q, int N) {
    int i = blockIdx.x * blockDim.x + threadIdx.x;
    if (i < N) {
        float dv = dinv[i];
        float s1 = (agg1[i] + u[i]) * dv;
        float c0 = 0.f, c1 = 0.f;
#pragma unroll
        for (int k = 0; k < 16; ++k) {
            float h = fmaxf(fmaf(s1, W1[k], b1[k]), 0.f);
            c0 = fmaf(h, W2[2 * k], c0);
            c1 = fmaf(h, W2[2 * k + 1], c1);
        }
        q[i] = make_float2(c0 * dv, c1 * dv);
    }
}
__global__ __launch_bounds__(NT) void fb_edge2(const int* __restrict__ src,
                                               const int* __restrict__ dst,
                                               const float2* __restrict__ q,
                                               float* __restrict__ agg2, int E) {
    int e = blockIdx.x * blockDim.x + threadIdx.x;
    if (e < E) {
        float2 qq = q[src[e]];
        atomicAdd(&agg2[2 * dst[e]], qq.x);
        atomicAdd(&agg2[2 * dst[e] + 1], qq.y);
    }
}
__global__ __launch_bounds__(NT) void fb_node3(const float* __restrict__ agg2,
                                               const float2* __restrict__ q,
                                               const float* __restrict__ dinv,
                                               const float* __restrict__ b2,
                                               float2* __restrict__ out, int N) {
    int i = blockIdx.x * blockDim.x + threadIdx.x;
    if (i < N) {
        float dv = dinv[i];
        float2 qi = q[i];
        float o0 = (agg2[2 * i] + qi.x) * dv + b2[0];
        float o1 = (agg2[2 * i + 1] + qi.y) * dv + b2[1];
        float m = fmaxf(o0, o1);
        float l = m + logf(expf(o0 - m) + expf(o1 - m));
        out[i] = make_float2(o0 - l, o1 - l);
    }
}

// ===========================================================================
extern "C" void kernel_launch(void* const* d_in, const int* in_sizes, int n_in,
                              void* d_out, int out_size, void* d_ws, size_t ws_size,
                              hipStream_t stream) {
    const float* x  = (const float*)d_in[0];
    const int* ei   = (const int*)d_in[1];
    const float* W1 = (const float*)d_in[2];
    const float* b1 = (const float*)d_in[3];
    const float* W2 = (const float*)d_in[4];
    const float* b2 = (const float*)d_in[5];

    const int N = in_sizes[0];
    const int E = in_sizes[1] / 2;
    const int* src = ei;
    const int* dst = ei + E;

    const int nbucket = (N + NPB - 1) / NPB;
    const int cap = ((E / nbucket + 1024) + 63) & ~63;   // must be <= SORT_CAP

    auto align_up = [](size_t v) { return (v + 255) & ~(size_t)255; };
    size_t off_ctr   = 0;
    size_t off_file  = align_up((size_t)MAXB * sizeof(int));
    size_t off_start = align_up(off_file + (size_t)nbucket * SORT_CAP * sizeof(unsigned int));
    size_t off_dinv  = align_up(off_start + (size_t)nbucket * (NPB + 1) * sizeof(int));
    size_t off_u     = align_up(off_dinv + (size_t)N * sizeof(float));
    size_t off_q     = align_up(off_u + (size_t)N * sizeof(unsigned short));
    size_t needed    = off_q + (size_t)N * sizeof(unsigned int);

    char* ws = (char*)d_ws;

    if (nbucket <= MAXB && cap <= SORT_CAP && needed <= ws_size) {
        int*            ctr   = (int*)(ws + off_ctr);
        unsigned int*   file  = (unsigned int*)(ws + off_file);
        int*            start = (int*)(ws + off_start);
        float*          dinv  = (float*)(ws + off_dinv);
        unsigned short* u     = (unsigned short*)(ws + off_u);
        unsigned int*   q     = (unsigned int*)(ws + off_q);

        (void)hipMemsetAsync(ctr, 0, (size_t)MAXB * sizeof(int), stream);

        const int p1Blocks  = (E + CHUNK - 1) / CHUNK;
        const int nodBlocks = (N + 255) / 256;
        k_bucket<<<p1Blocks, P1T, 0, stream>>>(src, dst, file, ctr, E, nbucket, SORT_CAP);
        k_sort  <<<nbucket, NPB, 0, stream>>>(file, ctr, start, x, dinv, u, N, SORT_CAP);
        k_agg1  <<<nodBlocks, 256, 0, stream>>>(file, start, u, dinv, W1, b1, W2, q, N, SORT_CAP);
        k_agg2  <<<nodBlocks, 256, 0, stream>>>(file, start, q, dinv, b2, (float2*)d_out, N, SORT_CAP);
    } else {
        int*    deg  = (int*)   (ws);
        float*  agg1 = (float*) (ws + (size_t)4 * N);
        float*  agg2 = (float*) (ws + (size_t)8 * N);
        float*  dinv = (float*) (ws + (size_t)16 * N);
        float*  u    = (float*) (ws + (size_t)20 * N);
        float2* q    = (float2*)(ws + (size_t)24 * N);
        (void)hipMemsetAsync(ws, 0, (size_t)16 * N, stream);
        const int nodeBlocks = (N + NT - 1) / NT;
        const int edgeBlocks = (E + NT - 1) / NT;
        fb_deg  <<<edgeBlocks, NT, 0, stream>>>(dst, deg, E);
        fb_node1<<<nodeBlocks, NT, 0, stream>>>(x, deg, dinv, u, N);
        fb_edge1<<<edgeBlocks, NT, 0, stream>>>(src, dst, u, agg1, E);
        fb_node2<<<nodeBlocks, NT, 0, stream>>>(agg1, u, dinv, W1, b1, W2, q, N);
        fb_edge2<<<edgeBlocks, NT, 0, stream>>>(src, dst, q, agg2, E);
        fb_node3<<<nodeBlocks, NT, 0, stream>>>(agg2, q, dinv, b2, (float2*)d_out, N);
    }
}

// Round 10
// 239.253 us; speedup vs baseline: 1.1971x; 1.1971x over previous
//
#include <hip/hip_runtime.h>
#include <math.h>

// ---------------------------------------------------------------------------
// Pipeline v6 — two-level dst sort + scalar-CSR aggregation (cached walks).
// r9 lesson: nontemporal on the segment walk refetches each 64B line up to
// 4x (nt bypasses L2; sequential 16B touches of one line each refetch) —
// FETCH 52->89MB, agg2 49->73us. v6 = r9 with CACHED agg walks.
//   k_bucket : radix pass 1 (dst>>10), ONE LDS atomic/edge (rank-first,
//              rk[] doubles as histogram), shuffle scan, coalesced run
//              write-out (nt stores are fine: write-once).
//   k_sort   : radix pass 2 (dst&1023) per bucket; rank atomic == degree
//              histogram; in-place coalesced write-back; CSR start[];
//              fused dinv / u = bf16(x*dinv) epilogue.
//   k_agg1   : thread=node CSR walk, cached uint4-middle (head/tail scalar),
//              gather u (bf16), MLP 1->16->2, q packed 2xbf16.
//   k_agg2   : same walk on q; +self, *dinv, +b2, log_softmax.
// ---------------------------------------------------------------------------

typedef unsigned int uint4v __attribute__((ext_vector_type(4)));

#define NPB 1024            // nodes per bucket
#define NPB_SHIFT 10
#define NPB_MASK (NPB - 1)
#define MAXB 512            // max buckets
#define P1T 512             // k_bucket threads
#define CHUNK 16384         // edges per k_bucket block
#define EPT 32              // CHUNK / P1T edges per thread
#define SORT_CAP 17408      // per-bucket file capacity
#define SPT 17              // SORT_CAP / 1024 entries per k_sort thread

__device__ __forceinline__ unsigned short f2bf(float f) {
    unsigned int x = __float_as_uint(f);
    x += 0x7fffu + ((x >> 16) & 1u);            // round-to-nearest-even
    return (unsigned short)(x >> 16);
}
__device__ __forceinline__ float bf2f(unsigned short h) {
    return __uint_as_float((unsigned int)h << 16);
}

// ---------------------------------------------------------------------------
// Phase 1: bucket by dst>>10. One LDS atomic per edge (rank-first).
// ---------------------------------------------------------------------------
__global__ __launch_bounds__(P1T) void k_bucket(
    const int* __restrict__ src, const int* __restrict__ dst,
    unsigned int* __restrict__ file, int* __restrict__ ctr,
    int E, int nbucket, int cap)
{
    __shared__ unsigned int sorted[CHUNK];   // 64 KB
    __shared__ int rk[MAXB];                 // rank counters -> histogram
    __shared__ int pre[MAXB + 1];
    __shared__ int gb[MAXB];
    __shared__ int wsum[P1T / 64];

    const int t  = threadIdx.x;
    const int e0 = blockIdx.x * CHUNK;
    const int nE = min(CHUNK, E - e0);

    for (int b = t; b < MAXB; b += P1T) rk[b] = 0;
    __syncthreads();

    const bool full = (nE == CHUNK);
    int4 dc[8];          // cached dst
    int  rnk[EPT];       // cached ranks

    // ---- pass 1: rank assignment (doubles as histogram) ----
    if (full) {
        const int4* d4 = (const int4*)(dst + e0);
#pragma unroll
        for (int k = 0; k < 8; ++k) dc[k] = d4[t + k * P1T];
#pragma unroll
        for (int k = 0; k < 8; ++k) {
            rnk[4 * k]     = atomicAdd(&rk[((unsigned)dc[k].x) >> NPB_SHIFT], 1);
            rnk[4 * k + 1] = atomicAdd(&rk[((unsigned)dc[k].y) >> NPB_SHIFT], 1);
            rnk[4 * k + 2] = atomicAdd(&rk[((unsigned)dc[k].z) >> NPB_SHIFT], 1);
            rnk[4 * k + 3] = atomicAdd(&rk[((unsigned)dc[k].w) >> NPB_SHIFT], 1);
        }
    } else {
        int k = 0;
        for (int i = t; i < nE; i += P1T, ++k)
            rnk[k] = atomicAdd(&rk[((unsigned)dst[e0 + i]) >> NPB_SHIFT], 1);
    }
    __syncthreads();

    // ---- hierarchical inclusive scan of rk -> pre (3 barriers) ----
    {
        const int lane = t & 63, wv = t >> 6;
        int v = (t < nbucket) ? rk[t] : 0;
#pragma unroll
        for (int d = 1; d < 64; d <<= 1) {
            int nv = __shfl_up(v, d, 64);
            if (lane >= d) v += nv;
        }
        if (lane == 63) wsum[wv] = v;
        __syncthreads();
        if (t < P1T / 64) {
            int s = wsum[t];
#pragma unroll
            for (int d = 1; d < P1T / 64; d <<= 1) {
                int ns = __shfl_up(s, d, P1T / 64);
                if (t >= d) s += ns;
            }
            wsum[t] = s;
        }
        __syncthreads();
        pre[t + 1] = (wv ? wsum[wv - 1] : 0) + v;
        if (t == 0) pre[0] = 0;
    }
    __syncthreads();

    // ---- reserve global space per (block,bucket) ----
    for (int b = t; b < nbucket; b += P1T) {
        int c = pre[b + 1] - pre[b];
        gb[b] = c ? atomicAdd(&ctr[b], c) : 0;
    }
    __syncthreads();

    // ---- pass 2: scatter into LDS using saved ranks (no atomics) ----
    if (full) {
        const int4* s4 = (const int4*)(src + e0);
#pragma unroll
        for (int k = 0; k < 8; ++k) {
            int4 s = s4[t + k * P1T];
            int4 d = dc[k];
            sorted[pre[((unsigned)d.x) >> NPB_SHIFT] + rnk[4 * k]] =
                (((unsigned)s.x) << NPB_SHIFT) | ((unsigned)d.x & NPB_MASK);
            sorted[pre[((unsigned)d.y) >> NPB_SHIFT] + rnk[4 * k + 1]] =
                (((unsigned)s.y) << NPB_SHIFT) | ((unsigned)d.y & NPB_MASK);
            sorted[pre[((unsigned)d.z) >> NPB_SHIFT] + rnk[4 * k + 2]] =
                (((unsigned)s.z) << NPB_SHIFT) | ((unsigned)d.z & NPB_MASK);
            sorted[pre[((unsigned)d.w) >> NPB_SHIFT] + rnk[4 * k + 3]] =
                (((unsigned)s.w) << NPB_SHIFT) | ((unsigned)d.w & NPB_MASK);
        }
    } else {
        int k = 0;
        for (int i = t; i < nE; i += P1T, ++k) {
            int d = dst[e0 + i];
            int b = ((unsigned)d) >> NPB_SHIFT;
            sorted[pre[b] + rnk[k]] =
                (((unsigned)src[e0 + i]) << NPB_SHIFT) | ((unsigned)d & NPB_MASK);
        }
    }
    __syncthreads();

    // ---- pass 3: per-wave run write-out, clamped to cap ----
    {
        const int wid  = t >> 6;
        const int lane = t & 63;
        const int nw   = P1T >> 6;
        for (int b = wid; b < nbucket; b += nw) {
            int s0 = pre[b], s1 = pre[b + 1];
            int base = gb[b];
            unsigned int* dp = file + (size_t)b * cap;
            for (int j = s0 + lane; j < s1; j += 64) {
                int idx = base + (j - s0);
                if (idx < cap)
                    __builtin_nontemporal_store(sorted[j], &dp[idx]);
            }
        }
    }
}

// ---------------------------------------------------------------------------
// Phase 2: per-bucket sort by dstlo; rank atomic == degree histogram.
// ---------------------------------------------------------------------------
__global__ __launch_bounds__(NPB) void k_sort(
    unsigned int* __restrict__ file, const int* __restrict__ ctr,
    int* __restrict__ start, const float* __restrict__ x,
    float* __restrict__ dinv, unsigned short* __restrict__ u,
    int N, int cap)
{
    __shared__ unsigned int sorted[SORT_CAP];  // 69.6 KB
    __shared__ int cnt[NPB];
    __shared__ int pre[NPB + 1];
    __shared__ int wsum[NPB / 64];

    const int t = threadIdx.x;
    const int b = blockIdx.x;
    const int nb = min(ctr[b], cap);
    unsigned int* f = file + (size_t)b * cap;

    cnt[t] = 0;
    __syncthreads();

    unsigned int ev[SPT];
    int rk_[SPT];
#pragma unroll
    for (int k = 0; k < SPT; ++k) {
        int i = t + (k << NPB_SHIFT);
        if (i < nb) ev[k] = f[i];
    }
#pragma unroll
    for (int k = 0; k < SPT; ++k) {
        int i = t + (k << NPB_SHIFT);
        if (i < nb) rk_[k] = atomicAdd(&cnt[ev[k] & NPB_MASK], 1);
    }
    __syncthreads();

    // hierarchical inclusive scan of cnt -> pre (3 barriers)
    {
        const int lane = t & 63, wv = t >> 6;
        int v = cnt[t];
#pragma unroll
        for (int d = 1; d < 64; d <<= 1) {
            int nv = __shfl_up(v, d, 64);
            if (lane >= d) v += nv;
        }
        if (lane == 63) wsum[wv] = v;
        __syncthreads();
        if (t < NPB / 64) {
            int s = wsum[t];
#pragma unroll
            for (int d = 1; d < NPB / 64; d <<= 1) {
                int ns = __shfl_up(s, d, NPB / 64);
                if (t >= d) s += ns;
            }
            wsum[t] = s;
        }
        __syncthreads();
        pre[t + 1] = (wv ? wsum[wv - 1] : 0) + v;
        if (t == 0) pre[0] = 0;
    }
    __syncthreads();

    // scatter src into dst-sorted LDS order
#pragma unroll
    for (int k = 0; k < SPT; ++k) {
        int i = t + (k << NPB_SHIFT);
        if (i < nb)
            sorted[pre[ev[k] & NPB_MASK] + rk_[k]] = ev[k] >> NPB_SHIFT;
    }
    __syncthreads();

    // coalesced in-place write-back (nt ok: consumed a kernel later via L2
    // anyway, and written exactly once)
    for (int i = t; i < nb; i += NPB)
        __builtin_nontemporal_store(sorted[i], &f[i]);

    // CSR offsets
    start[b * (NPB + 1) + t] = pre[t];
    if (t == 0) start[b * (NPB + 1) + NPB] = pre[NPB];

    // node epilogue
    const int g = b * NPB + t;
    if (g < N) {
        float dv = rsqrtf((float)(cnt[t] + 1));   // +1 self-loop
        dinv[g] = dv;
        u[g] = f2bf(x[g] * dv);
    }
}

// ---------------------------------------------------------------------------
// Phase 3: scalar-CSR agg1, CACHED uint4-middle walk -> MLP -> q (2xbf16).
// ---------------------------------------------------------------------------
__global__ __launch_bounds__(256) void k_agg1(
    const unsigned int* __restrict__ file, const int* __restrict__ start,
    const unsigned short* __restrict__ u, const float* __restrict__ dinv,
    const float* __restrict__ W1, const float* __restrict__ b1,
    const float* __restrict__ W2, unsigned int* __restrict__ q,
    int N, int cap)
{
    int g = blockIdx.x * 256 + threadIdx.x;
    if (g >= N) return;
    int b = g >> NPB_SHIFT, loc = g & NPB_MASK;
    const int* st = start + b * (NPB + 1);
    int e0 = st[loc], e1 = st[loc + 1];
    const unsigned int* f = file + (size_t)b * cap;

    float acc = 0.f;
    int j = e0;
    int ja = (e0 + 3) & ~3;   // first 16B-aligned index
    int jb = e1 & ~3;         // last aligned block end
    if (ja > jb) ja = e1;     // tiny segment: all scalar
    for (; j < ja; ++j) acc += bf2f(u[f[j]]);
    for (; j < jb; j += 4) {
        uint4v w = *(const uint4v*)(f + j);
        float v0 = bf2f(u[w.x]), v1 = bf2f(u[w.y]);
        float v2 = bf2f(u[w.z]), v3 = bf2f(u[w.w]);
        acc += (v0 + v1) + (v2 + v3);
    }
    for (; j < e1; ++j) acc += bf2f(u[f[j]]);

    float dv = dinv[g];
    float s1v = (acc + bf2f(u[g])) * dv;
    float c0 = 0.f, c1 = 0.f;
#pragma unroll
    for (int k = 0; k < 16; ++k) {
        float h = fmaxf(fmaf(s1v, W1[k], b1[k]), 0.f);
        c0 = fmaf(h, W2[2 * k], c0);
        c1 = fmaf(h, W2[2 * k + 1], c1);
    }
    q[g] = (unsigned int)f2bf(c0 * dv) | ((unsigned int)f2bf(c1 * dv) << 16);
}

// ---------------------------------------------------------------------------
// Phase 4: scalar-CSR agg2, CACHED uint4-middle walk -> log_softmax.
// ---------------------------------------------------------------------------
__global__ __launch_bounds__(256) void k_agg2(
    const unsigned int* __restrict__ file, const int* __restrict__ start,
    const unsigned int* __restrict__ q, const float* __restrict__ dinv,
    const float* __restrict__ b2, float2* __restrict__ out,
    int N, int cap)
{
    int g = blockIdx.x * 256 + threadIdx.x;
    if (g >= N) return;
    int b = g >> NPB_SHIFT, loc = g & NPB_MASK;
    const int* st = start + b * (NPB + 1);
    int e0 = st[loc], e1 = st[loc + 1];
    const unsigned int* f = file + (size_t)b * cap;

    float a0 = 0.f, a1 = 0.f;
    int j = e0;
    int ja = (e0 + 3) & ~3;
    int jb = e1 & ~3;
    if (ja > jb) ja = e1;
    for (; j < ja; ++j) {
        unsigned int gq = q[f[j]];
        a0 += bf2f((unsigned short)gq);
        a1 += bf2f((unsigned short)(gq >> 16));
    }
    for (; j < jb; j += 4) {
        uint4v w = *(const uint4v*)(f + j);
        unsigned int g0 = q[w.x], g1 = q[w.y], g2 = q[w.z], g3 = q[w.w];
        a0 += (bf2f((unsigned short)g0) + bf2f((unsigned short)g1)) +
              (bf2f((unsigned short)g2) + bf2f((unsigned short)g3));
        a1 += (bf2f((unsigned short)(g0 >> 16)) + bf2f((unsigned short)(g1 >> 16))) +
              (bf2f((unsigned short)(g2 >> 16)) + bf2f((unsigned short)(g3 >> 16)));
    }
    for (; j < e1; ++j) {
        unsigned int gq = q[f[j]];
        a0 += bf2f((unsigned short)gq);
        a1 += bf2f((unsigned short)(gq >> 16));
    }

    float dv = dinv[g];
    unsigned int qi = q[g];
    float o0 = (a0 + bf2f((unsigned short)qi)) * dv + b2[0];
    float o1 = (a1 + bf2f((unsigned short)(qi >> 16))) * dv + b2[1];
    float m = fmaxf(o0, o1);
    float l = m + logf(expf(o0 - m) + expf(o1 - m));
    out[g] = make_float2(o0 - l, o1 - l);
}

// ===========================================================================
// Fallback path (direct-atomic, fp32) if workspace/shape doesn't fit.
// ===========================================================================
#define NT 256
__global__ __launch_bounds__(NT) void fb_deg(const int* __restrict__ dst,
                                             int* __restrict__ deg, int E) {
    int e = blockIdx.x * blockDim.x + threadIdx.x;
    if (e < E) atomicAdd(&deg[dst[e]], 1);
}
__global__ __launch_bounds__(NT) void fb_node1(const float* __restrict__ x,
                                               const int* __restrict__ deg,
                                               float* __restrict__ dinv,
                                               float* __restrict__ u, int N) {
    int i = blockIdx.x * blockDim.x + threadIdx.x;
    if (i < N) {
        float dv = rsqrtf((float)(deg[i] + 1));
        dinv[i] = dv;
        u[i] = x[i] * dv;
    }
}
__global__ __launch_bounds__(NT) void fb_edge1(const int* __restrict__ src,
                                               const int* __restrict__ dst,
                                               const float* __restrict__ u,
                                               float* __restrict__ agg1, int E) {
    int e = blockIdx.x * blockDim.x + threadIdx.x;
    if (e < E) atomicAdd(&agg1[dst[e]], u[src[e]]);
}
__global__ __launch_bounds__(NT) void fb_node2(const float* __restrict__ agg1,
                                               const float* __restrict__ u,
                                               const float* __restrict__ dinv,
                                               const float* __restrict__ W1,
                                               const float* __restrict__ b1,
                                               const float* __restrict__ W2,
                                               float2* __restrict__ q, int N) {
    int i = blockIdx.x * blockDim.x + threadIdx.x;
    if (i < N) {
        float dv = dinv[i];
        float s1 = (agg1[i] + u[i]) * dv;
        float c0 = 0.f, c1 = 0.f;
#pragma unroll
        for (int k = 0; k < 16; ++k) {
            float h = fmaxf(fmaf(s1, W1[k], b1[k]), 0.f);
            c0 = fmaf(h, W2[2 * k], c0);
            c1 = fmaf(h, W2[2 * k + 1], c1);
        }
        q[i] = make_float2(c0 * dv, c1 * dv);
    }
}
__global__ __launch_bounds__(NT) void fb_edge2(const int* __restrict__ src,
                                               const int* __restrict__ dst,
                                               const float2* __restrict__ q,
                                               float* __restrict__ agg2, int E) {
    int e = blockIdx.x * blockDim.x + threadIdx.x;
    if (e < E) {
        float2 qq = q[src[e]];
        atomicAdd(&agg2[2 * dst[e]], qq.x);
        atomicAdd(&agg2[2 * dst[e] + 1], qq.y);
    }
}
__global__ __launch_bounds__(NT) void fb_node3(const float* __restrict__ agg2,
                                               const float2* __restrict__ q,
                                               const float* __restrict__ dinv,
                                               const float* __restrict__ b2,
                                               float2* __restrict__ out, int N) {
    int i = blockIdx.x * blockDim.x + threadIdx.x;
    if (i < N) {
        float dv = dinv[i];
        float2 qi = q[i];
        float o0 = (agg2[2 * i] + qi.x) * dv + b2[0];
        float o1 = (agg2[2 * i + 1] + qi.y) * dv + b2[1];
        float m = fmaxf(o0, o1);
        float l = m + logf(expf(o0 - m) + expf(o1 - m));
        out[i] = make_float2(o0 - l, o1 - l);
    }
}

// ===========================================================================
extern "C" void kernel_launch(void* const* d_in, const int* in_sizes, int n_in,
                              void* d_out, int out_size, void* d_ws, size_t ws_size,
                              hipStream_t stream) {
    const float* x  = (const float*)d_in[0];
    const int* ei   = (const int*)d_in[1];
    const float* W1 = (const float*)d_in[2];
    const float* b1 = (const float*)d_in[3];
    const float* W2 = (const float*)d_in[4];
    const float* b2 = (const float*)d_in[5];

    const int N = in_sizes[0];
    const int E = in_sizes[1] / 2;
    const int* src = ei;
    const int* dst = ei + E;

    const int nbucket = (N + NPB - 1) / NPB;
    const int cap = ((E / nbucket + 1024) + 63) & ~63;   // must be <= SORT_CAP

    auto align_up = [](size_t v) { return (v + 255) & ~(size_t)255; };
    size_t off_ctr   = 0;
    size_t off_file  = align_up((size_t)MAXB * sizeof(int));
    size_t off_start = align_up(off_file + (size_t)nbucket * SORT_CAP * sizeof(unsigned int));
    size_t off_dinv  = align_up(off_start + (size_t)nbucket * (NPB + 1) * sizeof(int));
    size_t off_u     = align_up(off_dinv + (size_t)N * sizeof(float));
    size_t off_q     = align_up(off_u + (size_t)N * sizeof(unsigned short));
    size_t needed    = off_q + (size_t)N * sizeof(unsigned int);

    char* ws = (char*)d_ws;

    if (nbucket <= MAXB && cap <= SORT_CAP && needed <= ws_size) {
        int*            ctr   = (int*)(ws + off_ctr);
        unsigned int*   file  = (unsigned int*)(ws + off_file);
        int*            start = (int*)(ws + off_start);
        float*          dinv  = (float*)(ws + off_dinv);
        unsigned short* u     = (unsigned short*)(ws + off_u);
        unsigned int*   q     = (unsigned int*)(ws + off_q);

        (void)hipMemsetAsync(ctr, 0, (size_t)MAXB * sizeof(int), stream);

        const int p1Blocks  = (E + CHUNK - 1) / CHUNK;
        const int nodBlocks = (N + 255) / 256;
        k_bucket<<<p1Blocks, P1T, 0, stream>>>(src, dst, file, ctr, E, nbucket, SORT_CAP);
        k_sort  <<<nbucket, NPB, 0, stream>>>(file, ctr, start, x, dinv, u, N, SORT_CAP);
        k_agg1  <<<nodBlocks, 256, 0, stream>>>(file, start, u, dinv, W1, b1, W2, q, N, SORT_CAP);
        k_agg2  <<<nodBlocks, 256, 0, stream>>>(file, start, q, dinv, b2, (float2*)d_out, N, SORT_CAP);
    } else {
        int*    deg  = (int*)   (ws);
        float*  agg1 = (float*) (ws + (size_t)4 * N);
        float*  agg2 = (float*) (ws + (size_t)8 * N);
        float*  dinv = (float*) (ws + (size_t)16 * N);
        float*  u    = (float*) (ws + (size_t)20 * N);
        float2* q    = (float2*)(ws + (size_t)24 * N);
        (void)hipMemsetAsync(ws, 0, (size_t)16 * N, stream);
        const int nodeBlocks = (N + NT - 1) / NT;
        const int edgeBlocks = (E + NT - 1) / NT;
        fb_deg  <<<edgeBlocks, NT, 0, stream>>>(dst, deg, E);
        fb_node1<<<nodeBlocks, NT, 0, stream>>>(x, deg, dinv, u, N);
        fb_edge1<<<edgeBlocks, NT, 0, stream>>>(src, dst, u, agg1, E);
        fb_node2<<<nodeBlocks, NT, 0, stream>>>(agg1, u, dinv, W1, b1, W2, q, N);
        fb_edge2<<<edgeBlocks, NT, 0, stream>>>(src, dst, q, agg2, E);
        fb_node3<<<nodeBlocks, NT, 0, stream>>>(agg2, q, dinv, b2, (float2*)d_out, N);
    }
}